// Round 9
// baseline (481.239 us; speedup 1.0000x reference)
//
#include <hip/hip_runtime.h>

// B=4, C=256, C8=32, N=4096. fp16 MFMA: 16x16x32 (S, proj), 32x32x16 (PV).
#define BB 4
#define CC 256
#define NN 4096

typedef _Float16 half_t;
typedef __attribute__((ext_vector_type(8))) _Float16 half8;
typedef __attribute__((ext_vector_type(4))) _Float16 half4;
typedef __attribute__((ext_vector_type(4))) float floatx4;
typedef __attribute__((ext_vector_type(16))) float floatx16;

// ---------------------------------------------------------------------------
// cvt_w: cast the six weight matrices to fp16. grid (64, 6).
// ---------------------------------------------------------------------------
__global__ __launch_bounds__(256)
void cvt_w_kernel(const float* __restrict__ Wfx, const float* __restrict__ Wgx,
                  const float* __restrict__ Whx, const float* __restrict__ Wfy,
                  const float* __restrict__ Wgy, const float* __restrict__ Why,
                  half_t* __restrict__ oWfx, half_t* __restrict__ oWgx,
                  half_t* __restrict__ oWhx, half_t* __restrict__ oWfy,
                  half_t* __restrict__ oWgy, half_t* __restrict__ oWhy)
{
    const float* src; half_t* dst; int n;
    switch (blockIdx.y) {
        case 0: src = Wfx; dst = oWfx; n = 32 * CC; break;
        case 1: src = Wgx; dst = oWgx; n = 32 * CC; break;
        case 2: src = Whx; dst = oWhx; n = CC * CC; break;
        case 3: src = Wfy; dst = oWfy; n = 32 * CC; break;
        case 4: src = Wgy; dst = oWgy; n = 32 * CC; break;
        default: src = Why; dst = oWhy; n = CC * CC; break;
    }
    int idx = (blockIdx.x * 256 + threadIdx.x) * 4;
    if (idx >= n) return;
    float4 v = *(const float4*)&src[idx];
    half4 h; h[0] = (half_t)v.x; h[1] = (half_t)v.y; h[2] = (half_t)v.z; h[3] = (half_t)v.w;
    *(half4*)&dst[idx] = h;
}

// ---------------------------------------------------------------------------
// prep (fused transpose_cvt + proj_fg + proj_h): per block, stage
// xT[64n][256c] fp16 in LDS, then compute fT/gT and h for this 64-n tile.
// h is written in PV-FRAGMENT layout: hF[b][T][ch][c][16] with
// offset = ((T*4 + ch)*256 + c)*16 + (n & 15), T = n-tile, ch = (n>>4)&3.
// grid (64, 4, 2): y=b, z=sel. 512 thr, 8 waves, 34 KB LDS.
// ---------------------------------------------------------------------------
__global__ __launch_bounds__(512, 4)
void prep_kernel(const float* __restrict__ x, const float* __restrict__ y,
                 const half_t* __restrict__ Wfx, const half_t* __restrict__ Wgx,
                 const half_t* __restrict__ Whx, const half_t* __restrict__ Wfy,
                 const half_t* __restrict__ Wgy, const half_t* __restrict__ Why,
                 const float* __restrict__ bfx, const float* __restrict__ bgx,
                 const float* __restrict__ bhx, const float* __restrict__ bfy,
                 const float* __restrict__ bgy, const float* __restrict__ bhy,
                 half_t* __restrict__ fxT, half_t* __restrict__ gxT,
                 half_t* __restrict__ hx,
                 half_t* __restrict__ fyT, half_t* __restrict__ gyT,
                 half_t* __restrict__ hy)
{
    __shared__ half_t xT[64][266];   // 34 KB; dword pitch 133 == 5 mod 32

    const int n0 = blockIdx.x * 64;
    const int b  = blockIdx.y;
    const int sel = blockIdx.z;
    const float* in = sel ? y : x;
    const half_t* Wf = sel ? Wfy : Wfx;
    const half_t* Wg = sel ? Wgy : Wgx;
    const half_t* Wh = sel ? Why : Whx;
    const float*  bf = sel ? bfy : bfx;
    const float*  bg = sel ? bgy : bgx;
    const float*  bh = sel ? bhy : bhx;
    half_t* fT = sel ? fyT : fxT;
    half_t* gT = sel ? gyT : gxT;
    half_t* h  = sel ? hy : hx;

    const int t = threadIdx.x;
    const int w = t >> 6, lane = t & 63;
    const int q = lane >> 4, mc = lane & 15;

    // ---- stage 1: coalesced fp32 load (float4 along n) + transpose to LDS
    {
        const int n4 = t & 15;      // float4 slot along n (16 x 4 = 64 n)
        const int cb = t >> 4;      // 0..31 ; rows cb + 32j
        const float* inb = in + (size_t)b * CC * NN + n0 + n4 * 4;
        #pragma unroll
        for (int j = 0; j < 8; ++j) {
            const int c = cb + 32 * j;
            float4 v = *(const float4*)&inb[(size_t)c * NN];
            xT[n4 * 4 + 0][c] = (half_t)v.x;
            xT[n4 * 4 + 1][c] = (half_t)v.y;
            xT[n4 * 4 + 2][c] = (half_t)v.z;
            xT[n4 * 4 + 3][c] = (half_t)v.w;
        }
    }
    __syncthreads();

    // ---- stage 2: f,g. wave w -> of = w>>1, n-half = (w&1)*32.
    {
        const int of  = w >> 1;                 // 0,1 -> f ; 2,3 -> g
        const int col = (of & 1) * 16 + mc;     // output channel
        const half_t* Ws = (of < 2) ? Wf : Wg;
        const float*  bs = (of < 2) ? bf : bg;
        half_t* dst = (of < 2) ? fT : gT;
        const float bv = bs[col];
        floatx4 accf[2] = {{bv, bv, bv, bv}, {bv, bv, bv, bv}};

        #pragma unroll
        for (int ks = 0; ks < 8; ++ks) {
            int k0 = ks * 32 + q * 8;
            half8 bfr = *(const half8*)&Ws[(size_t)col * CC + k0];
            #pragma unroll
            for (int e = 0; e < 2; ++e) {
                half8 af = *(const half8*)&xT[(w & 1) * 32 + e * 16 + mc][k0];
                accf[e] = __builtin_amdgcn_mfma_f32_16x16x32_f16(af, bfr, accf[e], 0, 0, 0);
            }
        }
        #pragma unroll
        for (int e = 0; e < 2; ++e)
            #pragma unroll
            for (int r = 0; r < 4; ++r) {
                int n = n0 + (w & 1) * 32 + e * 16 + q * 4 + r;
                dst[((size_t)b * NN + n) * 32 + col] = (half_t)accf[e][r];
            }
    }

    // ---- stage 3: h -> hF fragment layout. wave w -> o-strip w*32.
    {
        const int o0 = w * 32;
        const int Tt = n0 >> 6;     // n-tile index
        floatx4 acch[2][4];
        #pragma unroll
        for (int j = 0; j < 2; ++j) {
            floatx4 bv;
            #pragma unroll
            for (int r = 0; r < 4; ++r) bv[r] = bh[o0 + j * 16 + q * 4 + r];
            #pragma unroll
            for (int i = 0; i < 4; ++i) acch[j][i] = bv;
        }

        #pragma unroll
        for (int ks = 0; ks < 8; ++ks) {
            int k0 = ks * 32 + q * 8;
            half8 a0 = *(const half8*)&Wh[(size_t)(o0 + mc) * CC + k0];
            half8 a1 = *(const half8*)&Wh[(size_t)(o0 + 16 + mc) * CC + k0];
            #pragma unroll
            for (int i = 0; i < 4; ++i) {
                half8 bfr = *(const half8*)&xT[i * 16 + mc][k0];
                acch[0][i] = __builtin_amdgcn_mfma_f32_16x16x32_f16(a0, bfr, acch[0][i], 0, 0, 0);
                acch[1][i] = __builtin_amdgcn_mfma_f32_16x16x32_f16(a1, bfr, acch[1][i], 0, 0, 0);
            }
        }

        half_t* hb = h + (size_t)b * NN * CC;
        #pragma unroll
        for (int j = 0; j < 2; ++j)
            #pragma unroll
            for (int i = 0; i < 4; ++i)      // i = n-chunk within tile
                #pragma unroll
                for (int r = 0; r < 4; ++r) {
                    int o = o0 + j * 16 + q * 4 + r;
                    hb[((size_t)((Tt * 4 + i) * 256 + o) << 4) + mc] = (half_t)acch[j][i][r];
                }
    }
}

// ---------------------------------------------------------------------------
// stats: Llog2[n] = -log2( sum_m exp(S[n,m]) ). grid (128, 4, 2).
// ---------------------------------------------------------------------------
__global__ __launch_bounds__(256)
void stats_kernel(const half_t* __restrict__ fT0, const half_t* __restrict__ gT0,
                  const half_t* __restrict__ fT1, const half_t* __restrict__ gT1,
                  float* __restrict__ L0, float* __restrict__ L1)
{
    __shared__ float red_l[4][32];
    const int b  = blockIdx.y;
    const int sel = blockIdx.z;
    const half_t* fT = sel ? fT1 : fT0;
    const half_t* gT = sel ? gT1 : gT0;
    float* Lout = sel ? L1 : L0;

    const int n0 = blockIdx.x * 32;
    const int t  = threadIdx.x;
    const int w = t >> 6, lane = t & 63, q = lane >> 4, mc = lane & 15;
    const half_t* fTb = fT + (size_t)b * NN * 32;
    const half_t* gTb = gT + (size_t)b * NN * 32;

    half8 a0 = *(const half8*)&fTb[(size_t)(n0 + mc) * 32 + q * 8];
    half8 a1 = *(const half8*)&fTb[(size_t)(n0 + 16 + mc) * 32 + q * 8];

    float l0[4] = {0.f, 0.f, 0.f, 0.f}, l1[4] = {0.f, 0.f, 0.f, 0.f};
    for (int it = 0; it < NN / 64; ++it) {
        int m = (it * 4 + w) * 16 + mc;
        half8 bfr = *(const half8*)&gTb[(size_t)m * 32 + q * 8];
        floatx4 S0 = __builtin_amdgcn_mfma_f32_16x16x32_f16(a0, bfr, (floatx4){0.f,0.f,0.f,0.f}, 0, 0, 0);
        floatx4 S1 = __builtin_amdgcn_mfma_f32_16x16x32_f16(a1, bfr, (floatx4){0.f,0.f,0.f,0.f}, 0, 0, 0);
        #pragma unroll
        for (int r = 0; r < 4; ++r) { l0[r] += __expf(S0[r]); l1[r] += __expf(S1[r]); }
    }
    #pragma unroll
    for (int r = 0; r < 4; ++r) {
        #pragma unroll
        for (int off = 1; off < 16; off <<= 1) {
            l0[r] += __shfl_xor(l0[r], off);
            l1[r] += __shfl_xor(l1[r], off);
        }
    }
    if (mc == 0)
        #pragma unroll
        for (int r = 0; r < 4; ++r) {
            red_l[w][q * 4 + r]      = l0[r];
            red_l[w][16 + q * 4 + r] = l1[r];
        }
    __syncthreads();
    if (t < 32) {
        float L = red_l[0][t] + red_l[1][t] + red_l[2][t] + red_l[3][t];
        Lout[(size_t)b * NN + n0 + t] = -log2f(L);
    }
}

// ---------------------------------------------------------------------------
// pv: out[c,m] = src[c,m] + gamma * sum_n h[c,n] * exp2(S*log2e + Llog2[n]).
// v9 = v8 + A-frags prefetched ONE FULL TILE ahead (fix of R8's exposed
// global latency): Ar0/Ar1 register double-buffer, statically named.
// Body T (par): issue A(T+1)->Ar[opp]; f/L(T+2); S(T+1)->PT[opp];
// PV(T) consumes Ar[par] (loaded last body, full-body latency cover).
// grid (64, 8): block 64m x 256c, 8 waves, 2 blocks/CU, LDS = PT only 18 KB.
// VGPR ~96 (A dbuf 64 + acc 32 + f/L 24 + misc) -> <=128, no spill.
// ---------------------------------------------------------------------------
__global__ __launch_bounds__(512, 4)
void pv_kernel(const half_t* __restrict__ fT0, const half_t* __restrict__ gT0,
               const half_t* __restrict__ hF0, const float* __restrict__ L0,
               const float* __restrict__ src0, float* __restrict__ out0,
               const half_t* __restrict__ fT1, const half_t* __restrict__ gT1,
               const half_t* __restrict__ hF1, const float* __restrict__ L1,
               const float* __restrict__ src1, float* __restrict__ out1,
               const float* __restrict__ gamma)
{
    __shared__ half_t PT[2][64][72];     // 18 KB, double-buffered P^T[m][n]

    const int m0 = blockIdx.x * 64;
    const int b  = blockIdx.y & 3;
    const int sel = blockIdx.y >> 2;
    const half_t* fT = sel ? fT1 : fT0;
    const half_t* gT = sel ? gT1 : gT0;
    const half_t* hF = sel ? hF1 : hF0;
    const float*  Lg = sel ? L1 : L0;
    const float*  src = sel ? src1 : src0;
    float* out = sel ? out1 : out0;

    const int t = threadIdx.x;
    const int w = t >> 6, lane = t & 63;
    const int q = lane >> 4, mc = lane & 15;
    const int l5 = lane >> 5, l31 = lane & 31;

    const int smg = (w >> 1) * 16;     // S m-group (16 rows of 64)
    const int snh = (w & 1) * 32;      // S n-half (32 of 64)
    const int cg  = (w & 3) * 64;      // PV c-group
    const int mg  = (w >> 2) * 32;     // PV m-group

    const half_t* fTb = fT + (size_t)b * NN * 32;
    const half_t* gTb = gT + (size_t)b * NN * 32;
    const half_t* hFb = hF + (size_t)b * NN * CC;
    const float*  Lb  = Lg + (size_t)b * NN;

    // persistent S B-frag: m = m0 + smg + mc
    const half8 gS = *(const half8*)&gTb[(size_t)(m0 + smg + mc) * 32 + q * 8];

    // lane base pointers
    // A-frag (tile T, chunk ch, strip a): aP + (T*4+ch)*4096 + a*512
    const half_t* aP = hFb + (size_t)(cg + l31) * 16 + l5 * 8;
    const half_t* fP = fTb + (size_t)(snh + mc) * 32 + q * 8;   // + (nt + s*16)*32
    const float*  lP = Lb + snh + q * 4;                        // + nt + s*16

    floatx16 acc[2];
    #pragma unroll
    for (int a = 0; a < 2; ++a)
        #pragma unroll
        for (int r = 0; r < 16; ++r) acc[a][r] = 0.f;

    half8 Ar0[2][4], Ar1[2][4]; // A-frag double buffer [strip][chunk]
    half8 fr[2][2];             // f parity pipeline [par][s]
    floatx4 lr[2][2];

    // ---- prologue: P(0) -> PT[0]; Ar0 <- A(0); fr[0]/lr[0] <- f/L(1)
    {
        half8 f0[2]; floatx4 l0[2];
        #pragma unroll
        for (int s = 0; s < 2; ++s) {
            f0[s] = *(const half8*)&fP[(size_t)(s * 16) * 32];
            l0[s] = *(const floatx4*)&lP[s * 16];
        }
        #pragma unroll
        for (int s = 0; s < 2; ++s) {
            floatx4 S = __builtin_amdgcn_mfma_f32_16x16x32_f16(
                f0[s], gS, (floatx4){0.f, 0.f, 0.f, 0.f}, 0, 0, 0);
            half4 p;
            p[0] = (half_t)exp2f(fmaf(S[0], 1.44269504f, l0[s][0]));
            p[1] = (half_t)exp2f(fmaf(S[1], 1.44269504f, l0[s][1]));
            p[2] = (half_t)exp2f(fmaf(S[2], 1.44269504f, l0[s][2]));
            p[3] = (half_t)exp2f(fmaf(S[3], 1.44269504f, l0[s][3]));
            *(half4*)&PT[0][smg + mc][snh + s * 16 + q * 4] = p;
        }
    }
    #pragma unroll
    for (int a = 0; a < 2; ++a)
        #pragma unroll
        for (int c = 0; c < 4; ++c)
            Ar0[a][c] = *(const half8*)&aP[((size_t)c << 12) + a * 512];
    #pragma unroll
    for (int s = 0; s < 2; ++s) {
        fr[0][s] = *(const half8*)&fP[(size_t)(64 + s * 16) * 32];
        lr[0][s] = *(const floatx4*)&lP[64 + s * 16];
    }
    __syncthreads();

// body for tile T, parity par (PT[cur]=PT[par]):
//  1. issue A(T+1) -> Anxt (consumed NEXT body; full-body latency cover)
//  2. issue f/L(T+2) -> fr[opp]
//  3. S(T+1) from fr[par] -> PT[opp]   (VALU-heavy)
//  4. PV(T): Acur x PT[par]            (MFMA-heavy)
//  5. one barrier
#define PVBODY(T, par, opp, Acur, Anxt) {                                     \
    const int T1_ = ((T) + 1) & 63;                                           \
    const int T2_ = ((T) + 2) & 63;                                           \
    _Pragma("unroll")                                                         \
    for (int a_ = 0; a_ < 2; ++a_)                                            \
        _Pragma("unroll")                                                     \
        for (int c_ = 0; c_ < 4; ++c_)                                        \
            Anxt[a_][c_] = *(const half8*)&aP[((size_t)(T1_ * 4 + c_) << 12) + a_ * 512]; \
    _Pragma("unroll")                                                         \
    for (int s_ = 0; s_ < 2; ++s_) {                                          \
        fr[opp][s_] = *(const half8*)&fP[(size_t)(T2_ * 64 + s_ * 16) * 32];  \
        lr[opp][s_] = *(const floatx4*)&lP[T2_ * 64 + s_ * 16];               \
    }                                                                         \
    _Pragma("unroll")                                                         \
    for (int s_ = 0; s_ < 2; ++s_) {                                          \
        floatx4 S_ = __builtin_amdgcn_mfma_f32_16x16x32_f16(                  \
            fr[par][s_], gS, (floatx4){0.f, 0.f, 0.f, 0.f}, 0, 0, 0);         \
        half4 p_;                                                             \
        p_[0] = (half_t)exp2f(fmaf(S_[0], 1.44269504f, lr[par][s_][0]));      \
        p_[1] = (half_t)exp2f(fmaf(S_[1], 1.44269504f, lr[par][s_][1]));      \
        p_[2] = (half_t)exp2f(fmaf(S_[2], 1.44269504f, lr[par][s_][2]));      \
        p_[3] = (half_t)exp2f(fmaf(S_[3], 1.44269504f, lr[par][s_][3]));      \
        *(half4*)&PT[opp][smg + mc][snh + s_ * 16 + q * 4] = p_;              \
    }                                                                         \
    __builtin_amdgcn_s_setprio(1);                                            \
    _Pragma("unroll")                                                         \
    for (int c_ = 0; c_ < 4; ++c_) {                                          \
        half8 B_ = *(const half8*)&PT[par][mg + l31][c_ * 16 + l5 * 8];       \
        acc[0] = __builtin_amdgcn_mfma_f32_32x32x16_f16(Acur[0][c_], B_, acc[0], 0, 0, 0); \
        acc[1] = __builtin_amdgcn_mfma_f32_32x32x16_f16(Acur[1][c_], B_, acc[1], 0, 0, 0); \
    }                                                                         \
    __builtin_amdgcn_s_setprio(0);                                            \
    __syncthreads();                                                          \
}

    for (int T = 0; T < NN / 64; T += 2) {
        PVBODY(T, 0, 1, Ar0, Ar1);
        PVBODY(T + 1, 1, 0, Ar1, Ar0);
    }
    // (last body's S/A-prefetch compute wrapped-tile data; never consumed)

#undef PVBODY

    // ---- epilogue: out = src + gamma * acc (D: col=l31->m, row pattern->c)
    const float gm = gamma[0];
    const float* srcb = src + (size_t)b * CC * NN;
    float* outb = out + (size_t)b * CC * NN;
    const int m = m0 + mg + l31;
    #pragma unroll
    for (int a = 0; a < 2; ++a)
        #pragma unroll
        for (int r = 0; r < 16; ++r) {
            int c = cg + a * 32 + (r & 3) + 8 * (r >> 2) + 4 * l5;
            size_t idx = (size_t)c * NN + m;
            outb[idx] = fmaf(gm, acc[a][r], srcb[idx]);
        }
}

// ---------------------------------------------------------------------------
extern "C" void kernel_launch(void* const* d_in, const int* in_sizes, int n_in,
                              void* d_out, int out_size, void* d_ws, size_t ws_size,
                              hipStream_t stream)
{
    const float* x   = (const float*)d_in[0];
    const float* y   = (const float*)d_in[1];
    const float* Wfx = (const float*)d_in[2];
    const float* bfx = (const float*)d_in[3];
    const float* Wgx = (const float*)d_in[4];
    const float* bgx = (const float*)d_in[5];
    const float* Whx = (const float*)d_in[6];
    const float* bhx = (const float*)d_in[7];
    const float* Wfy = (const float*)d_in[8];
    const float* bfy = (const float*)d_in[9];
    const float* Wgy = (const float*)d_in[10];
    const float* bgy = (const float*)d_in[11];
    const float* Why = (const float*)d_in[12];
    const float* bhy = (const float*)d_in[13];
    const float* gam = (const float*)d_in[14];

    const size_t SZ_XT = (size_t)BB * NN * CC;   // 4,194,304 halves
    const size_t SZ_FG = (size_t)BB * NN * 32;   // 524,288 halves
    half_t* xTx   = (half_t*)d_ws;               // (unused, layout kept)
    half_t* xTy   = xTx + SZ_XT;
    half_t* hx    = xTy + SZ_XT;                 // hF fragment layout
    half_t* hy    = hx + SZ_XT;                  // hF fragment layout
    half_t* fxT   = hy + SZ_XT;
    half_t* gxT   = fxT + SZ_FG;
    half_t* fyT   = gxT + SZ_FG;
    half_t* gyT   = fyT + SZ_FG;
    half_t* Wfx_h = gyT + SZ_FG;
    half_t* Wgx_h = Wfx_h + 32 * CC;
    half_t* Wfy_h = Wgx_h + 32 * CC;
    half_t* Wgy_h = Wfy_h + 32 * CC;
    half_t* Whx_h = Wgy_h + 32 * CC;
    half_t* Why_h = Whx_h + CC * CC;
    float*  Lx    = (float*)(Why_h + CC * CC);
    float*  Ly    = Lx + (size_t)BB * NN;

    float* outx = (float*)d_out;
    float* outy = outx + (size_t)BB * CC * NN;

    cvt_w_kernel<<<dim3(64, 6), 256, 0, stream>>>(Wfx, Wgx, Whx, Wfy, Wgy, Why,
                                                  Wfx_h, Wgx_h, Whx_h, Wfy_h, Wgy_h, Why_h);

    prep_kernel<<<dim3(64, 4, 2), 512, 0, stream>>>(
        x, y, Wfx_h, Wgx_h, Whx_h, Wfy_h, Wgy_h, Why_h,
        bfx, bgx, bhx, bfy, bgy, bhy,
        fxT, gxT, hx, fyT, gyT, hy);

    // att_x rows: fy vs gx -> Lx ; att_y rows: fx vs gy -> Ly
    stats_kernel<<<dim3(128, 4, 2), 256, 0, stream>>>(fyT, gxT, fxT, gyT, Lx, Ly);

    pv_kernel<<<dim3(64, 8), 512, 0, stream>>>(
        fyT, gxT, hx, Lx, x, outx,
        fxT, gyT, hy, Ly, y, outy, gam);
}

// Round 10
// 253.633 us; speedup vs baseline: 1.8974x; 1.8974x over previous
//
#include <hip/hip_runtime.h>

// B=4, C=256, C8=32, N=4096. fp16 MFMA: 16x16x32 (S, proj), 32x32x16 (PV).
#define BB 4
#define CC 256
#define NN 4096

typedef _Float16 half_t;
typedef __attribute__((ext_vector_type(8))) _Float16 half8;
typedef __attribute__((ext_vector_type(4))) _Float16 half4;
typedef __attribute__((ext_vector_type(4))) float floatx4;
typedef __attribute__((ext_vector_type(16))) float floatx16;

// ---------------------------------------------------------------------------
// cvt_w: cast the six weight matrices to fp16. grid (64, 6).
// ---------------------------------------------------------------------------
__global__ __launch_bounds__(256)
void cvt_w_kernel(const float* __restrict__ Wfx, const float* __restrict__ Wgx,
                  const float* __restrict__ Whx, const float* __restrict__ Wfy,
                  const float* __restrict__ Wgy, const float* __restrict__ Why,
                  half_t* __restrict__ oWfx, half_t* __restrict__ oWgx,
                  half_t* __restrict__ oWhx, half_t* __restrict__ oWfy,
                  half_t* __restrict__ oWgy, half_t* __restrict__ oWhy)
{
    const float* src; half_t* dst; int n;
    switch (blockIdx.y) {
        case 0: src = Wfx; dst = oWfx; n = 32 * CC; break;
        case 1: src = Wgx; dst = oWgx; n = 32 * CC; break;
        case 2: src = Whx; dst = oWhx; n = CC * CC; break;
        case 3: src = Wfy; dst = oWfy; n = 32 * CC; break;
        case 4: src = Wgy; dst = oWgy; n = 32 * CC; break;
        default: src = Why; dst = oWhy; n = CC * CC; break;
    }
    int idx = (blockIdx.x * 256 + threadIdx.x) * 4;
    if (idx >= n) return;
    float4 v = *(const float4*)&src[idx];
    half4 h; h[0] = (half_t)v.x; h[1] = (half_t)v.y; h[2] = (half_t)v.z; h[3] = (half_t)v.w;
    *(half4*)&dst[idx] = h;
}

// ---------------------------------------------------------------------------
// prep (fused transpose_cvt + proj_fg + proj_h): per block, stage
// xT[64n][256c] fp16 in LDS, then compute fT/gT and h (plain [c][n]) for
// this 64-n tile. v10: h epilogue routed through LDS (hs alias of xT) so
// global h stores are 4x coalesced half8 per thread (was 32 scalar stores).
// grid (64, 4, 2): y=b, z=sel. 512 thr, 8 waves, 34 KB LDS.
// ---------------------------------------------------------------------------
__global__ __launch_bounds__(512, 4)
void prep_kernel(const float* __restrict__ x, const float* __restrict__ y,
                 const half_t* __restrict__ Wfx, const half_t* __restrict__ Wgx,
                 const half_t* __restrict__ Whx, const half_t* __restrict__ Wfy,
                 const half_t* __restrict__ Wgy, const half_t* __restrict__ Why,
                 const float* __restrict__ bfx, const float* __restrict__ bgx,
                 const float* __restrict__ bhx, const float* __restrict__ bfy,
                 const float* __restrict__ bgy, const float* __restrict__ bhy,
                 half_t* __restrict__ fxT, half_t* __restrict__ gxT,
                 half_t* __restrict__ hx,
                 half_t* __restrict__ fyT, half_t* __restrict__ gyT,
                 half_t* __restrict__ hy)
{
    __shared__ half_t xT[64][266];   // 34 KB; dword pitch 133 == 5 mod 32
    // epilogue alias: hs[256][66] (33 KB <= 34 KB), odd dword pitch 33
    half_t (*hs)[66] = (half_t(*)[66])&xT[0][0];

    const int n0 = blockIdx.x * 64;
    const int b  = blockIdx.y;
    const int sel = blockIdx.z;
    const float* in = sel ? y : x;
    const half_t* Wf = sel ? Wfy : Wfx;
    const half_t* Wg = sel ? Wgy : Wgx;
    const half_t* Wh = sel ? Why : Whx;
    const float*  bf = sel ? bfy : bfx;
    const float*  bg = sel ? bgy : bgx;
    const float*  bh = sel ? bhy : bhx;
    half_t* fT = sel ? fyT : fxT;
    half_t* gT = sel ? gyT : gxT;
    half_t* h  = sel ? hy : hx;

    const int t = threadIdx.x;
    const int w = t >> 6, lane = t & 63;
    const int q = lane >> 4, mc = lane & 15;

    // ---- stage 1: coalesced fp32 load (float4 along n) + transpose to LDS
    {
        const int n4 = t & 15;      // float4 slot along n (16 x 4 = 64 n)
        const int cb = t >> 4;      // 0..31 ; rows cb + 32j
        const float* inb = in + (size_t)b * CC * NN + n0 + n4 * 4;
        #pragma unroll
        for (int j = 0; j < 8; ++j) {
            const int c = cb + 32 * j;
            float4 v = *(const float4*)&inb[(size_t)c * NN];
            xT[n4 * 4 + 0][c] = (half_t)v.x;
            xT[n4 * 4 + 1][c] = (half_t)v.y;
            xT[n4 * 4 + 2][c] = (half_t)v.z;
            xT[n4 * 4 + 3][c] = (half_t)v.w;
        }
    }
    __syncthreads();

    // ---- stage 2: f,g. wave w -> of = w>>1, n-half = (w&1)*32.
    {
        const int of  = w >> 1;                 // 0,1 -> f ; 2,3 -> g
        const int col = (of & 1) * 16 + mc;     // output channel
        const half_t* Ws = (of < 2) ? Wf : Wg;
        const float*  bs = (of < 2) ? bf : bg;
        half_t* dst = (of < 2) ? fT : gT;
        const float bv = bs[col];
        floatx4 accf[2] = {{bv, bv, bv, bv}, {bv, bv, bv, bv}};

        #pragma unroll
        for (int ks = 0; ks < 8; ++ks) {
            int k0 = ks * 32 + q * 8;
            half8 bfr = *(const half8*)&Ws[(size_t)col * CC + k0];
            #pragma unroll
            for (int e = 0; e < 2; ++e) {
                half8 af = *(const half8*)&xT[(w & 1) * 32 + e * 16 + mc][k0];
                accf[e] = __builtin_amdgcn_mfma_f32_16x16x32_f16(af, bfr, accf[e], 0, 0, 0);
            }
        }
        #pragma unroll
        for (int e = 0; e < 2; ++e)
            #pragma unroll
            for (int r = 0; r < 4; ++r) {
                int n = n0 + (w & 1) * 32 + e * 16 + q * 4 + r;
                dst[((size_t)b * NN + n) * 32 + col] = (half_t)accf[e][r];
            }
    }

    // ---- stage 3: h GEMM (wave w -> o-strip w*32), epilogue through LDS.
    {
        const int o0 = w * 32;
        floatx4 acch[2][4];
        #pragma unroll
        for (int j = 0; j < 2; ++j) {
            floatx4 bv;
            #pragma unroll
            for (int r = 0; r < 4; ++r) bv[r] = bh[o0 + j * 16 + q * 4 + r];
            #pragma unroll
            for (int i = 0; i < 4; ++i) acch[j][i] = bv;
        }

        #pragma unroll
        for (int ks = 0; ks < 8; ++ks) {
            int k0 = ks * 32 + q * 8;
            half8 a0 = *(const half8*)&Wh[(size_t)(o0 + mc) * CC + k0];
            half8 a1 = *(const half8*)&Wh[(size_t)(o0 + 16 + mc) * CC + k0];
            #pragma unroll
            for (int i = 0; i < 4; ++i) {
                half8 bfr = *(const half8*)&xT[i * 16 + mc][k0];
                acch[0][i] = __builtin_amdgcn_mfma_f32_16x16x32_f16(a0, bfr, acch[0][i], 0, 0, 0);
                acch[1][i] = __builtin_amdgcn_mfma_f32_16x16x32_f16(a1, bfr, acch[1][i], 0, 0, 0);
            }
        }

        __syncthreads();     // all xT reads done; safe to overwrite as hs
        #pragma unroll
        for (int j = 0; j < 2; ++j)
            #pragma unroll
            for (int i = 0; i < 4; ++i)
                #pragma unroll
                for (int r = 0; r < 4; ++r) {
                    int o = o0 + j * 16 + q * 4 + r;
                    hs[o][i * 16 + mc] = (half_t)acch[j][i][r];
                }
        __syncthreads();     // hs complete

        // vector store: thread t -> row t>>1, n-half (t&1)*32 (4x half8)
        const int ro  = t >> 1;
        const int nh2 = (t & 1) * 32;
        half_t* hb = h + (size_t)b * CC * NN;
        #pragma unroll
        for (int k2 = 0; k2 < 4; ++k2) {
            half8 v = *(const half8*)&hs[ro][nh2 + k2 * 8];
            *(half8*)&hb[(size_t)ro * NN + n0 + nh2 + k2 * 8] = v;
        }
    }
}

// ---------------------------------------------------------------------------
// stats: Llog2[n] = -log2( sum_m exp(S[n,m]) ). grid (128, 4, 2).
// ---------------------------------------------------------------------------
__global__ __launch_bounds__(256)
void stats_kernel(const half_t* __restrict__ fT0, const half_t* __restrict__ gT0,
                  const half_t* __restrict__ fT1, const half_t* __restrict__ gT1,
                  float* __restrict__ L0, float* __restrict__ L1)
{
    __shared__ float red_l[4][32];
    const int b  = blockIdx.y;
    const int sel = blockIdx.z;
    const half_t* fT = sel ? fT1 : fT0;
    const half_t* gT = sel ? gT1 : gT0;
    float* Lout = sel ? L1 : L0;

    const int n0 = blockIdx.x * 32;
    const int t  = threadIdx.x;
    const int w = t >> 6, lane = t & 63, q = lane >> 4, mc = lane & 15;
    const half_t* fTb = fT + (size_t)b * NN * 32;
    const half_t* gTb = gT + (size_t)b * NN * 32;

    half8 a0 = *(const half8*)&fTb[(size_t)(n0 + mc) * 32 + q * 8];
    half8 a1 = *(const half8*)&fTb[(size_t)(n0 + 16 + mc) * 32 + q * 8];

    float l0[4] = {0.f, 0.f, 0.f, 0.f}, l1[4] = {0.f, 0.f, 0.f, 0.f};
    for (int it = 0; it < NN / 64; ++it) {
        int m = (it * 4 + w) * 16 + mc;
        half8 bfr = *(const half8*)&gTb[(size_t)m * 32 + q * 8];
        floatx4 S0 = __builtin_amdgcn_mfma_f32_16x16x32_f16(a0, bfr, (floatx4){0.f,0.f,0.f,0.f}, 0, 0, 0);
        floatx4 S1 = __builtin_amdgcn_mfma_f32_16x16x32_f16(a1, bfr, (floatx4){0.f,0.f,0.f,0.f}, 0, 0, 0);
        #pragma unroll
        for (int r = 0; r < 4; ++r) { l0[r] += __expf(S0[r]); l1[r] += __expf(S1[r]); }
    }
    #pragma unroll
    for (int r = 0; r < 4; ++r) {
        #pragma unroll
        for (int off = 1; off < 16; off <<= 1) {
            l0[r] += __shfl_xor(l0[r], off);
            l1[r] += __shfl_xor(l1[r], off);
        }
    }
    if (mc == 0)
        #pragma unroll
        for (int r = 0; r < 4; ++r) {
            red_l[w][q * 4 + r]      = l0[r];
            red_l[w][16 + q * 4 + r] = l1[r];
        }
    __syncthreads();
    if (t < 32) {
        float L = red_l[0][t] + red_l[1][t] + red_l[2][t] + red_l[3][t];
        Lout[(size_t)b * NN + n0 + t] = -log2f(L);
    }
}

// ---------------------------------------------------------------------------
// pv: out[c,m] = src[c,m] + gamma * sum_n h[c,n] * exp2(S*log2e + Llog2[n]).
// v7 (R7-verified, 113.7 us): square per-wave PV tile, ratio 1.0.
// grid (32, 8): block = 128m x 256c, 8 waves, 512 thr, 1 block/CU, 72 KB LDS.
// S: wave -> smg=(w>>1)*32 m, snh=(w&1)*32 n: 4 MFMA16, 16 exp/lane.
// PV: wave -> cg=(w&3)*64 c, pmg=(w>>2)*64 m: per k-chunk 2A+2B reads,
// 4 MFMA32. Merged S||PV interval, PT double-buffer, depth-1 reg pipeline,
// setprio around PV. acc[2][2]=64 VGPR -> launch_bounds(512,2), no spill.
// ---------------------------------------------------------------------------
__global__ __launch_bounds__(512, 2)
void pv_kernel(const half_t* __restrict__ fT0, const half_t* __restrict__ gT0,
               const half_t* __restrict__ h0, const float* __restrict__ L0,
               const float* __restrict__ src0, float* __restrict__ out0,
               const half_t* __restrict__ fT1, const half_t* __restrict__ gT1,
               const half_t* __restrict__ h1, const float* __restrict__ L1,
               const float* __restrict__ src1, float* __restrict__ out1,
               const float* __restrict__ gamma)
{
    __shared__ half_t h_lds[256][72];    // 36 KB, pitch 72 (proven)
    __shared__ half_t PT[2][128][72];    // 36 KB, double-buffered P^T[m][n]

    const int m0 = blockIdx.x * 128;
    const int b  = blockIdx.y & 3;
    const int sel = blockIdx.y >> 2;
    const half_t* fT = sel ? fT1 : fT0;
    const half_t* gT = sel ? gT1 : gT0;
    const half_t* h  = sel ? h1 : h0;
    const float*  Lg = sel ? L1 : L0;
    const float*  src = sel ? src1 : src0;
    float* out = sel ? out1 : out0;

    const int t = threadIdx.x;
    const int w = t >> 6, lane = t & 63;
    const int q = lane >> 4, mc = lane & 15;
    const int l5 = lane >> 5, l31 = lane & 31;

    const int smg = (w >> 1) * 32;     // S m-group (2 x 16 rows)
    const int snh = (w & 1) * 32;      // S n-half (2 x 16 cols)
    const int cg  = (w & 3) * 64;      // PV c-group
    const int pmg = (w >> 2) * 64;     // PV m-group

    const half_t* fTb = fT + (size_t)b * NN * 32;
    const half_t* gTb = gT + (size_t)b * NN * 32;
    const half_t* hb  = h + (size_t)b * CC * NN;
    const float*  Lb  = Lg + (size_t)b * NN;

    // persistent S B-frags: m = m0 + smg + u*16 + mc
    half8 gS[2];
    gS[0] = *(const half8*)&gTb[(size_t)(m0 + smg + mc) * 32 + q * 8];
    gS[1] = *(const half8*)&gTb[(size_t)(m0 + smg + 16 + mc) * 32 + q * 8];

    // h staging: thread covers rows srow + 64*i (i=0..3), chunk sch
    const int srow = t >> 3;    // 0..63
    const int sch  = t & 7;     // 0..7

    // lane base pointers
    const half_t* hP = hb + (size_t)srow * NN + sch * 8;        // + 64*i*NN + nt
    const half_t* fP = fTb + (size_t)(snh + mc) * 32 + q * 8;   // + (nt + s*16)*32
    const float*  lP = Lb + snh + q * 4;                        // + nt + s*16

    floatx16 acc[2][2];
    #pragma unroll
    for (int a = 0; a < 2; ++a)
        #pragma unroll
        for (int ms = 0; ms < 2; ++ms)
            #pragma unroll
            for (int r = 0; r < 16; ++r) acc[a][ms][r] = 0.f;

    half8 hpre[4];              // h tile in flight (stage next iter)
    half8 fu[2], ff[2];         // f: in-use (S this iter), in-flight
    floatx4 lvu[2], lvf[2];

    // ---- prologue: P(0) -> PT[0]; hpre(0); f(1)/lv(1) -> fu/lvu
    {
        half8 f0[2]; floatx4 l0[2];
        #pragma unroll
        for (int s = 0; s < 2; ++s) {
            f0[s] = *(const half8*)&fP[(size_t)(s * 16) * 32];
            l0[s] = *(const floatx4*)&lP[s * 16];
        }
        #pragma unroll
        for (int u = 0; u < 2; ++u)
            #pragma unroll
            for (int s = 0; s < 2; ++s) {
                floatx4 S = __builtin_amdgcn_mfma_f32_16x16x32_f16(
                    f0[s], gS[u], (floatx4){0.f, 0.f, 0.f, 0.f}, 0, 0, 0);
                half4 p;
                p[0] = (half_t)exp2f(fmaf(S[0], 1.44269504f, l0[s][0]));
                p[1] = (half_t)exp2f(fmaf(S[1], 1.44269504f, l0[s][1]));
                p[2] = (half_t)exp2f(fmaf(S[2], 1.44269504f, l0[s][2]));
                p[3] = (half_t)exp2f(fmaf(S[3], 1.44269504f, l0[s][3]));
                *(half4*)&PT[0][smg + u * 16 + mc][snh + s * 16 + q * 4] = p;
            }
    }
    #pragma unroll
    for (int i = 0; i < 4; ++i)
        hpre[i] = *(const half8*)&hP[(size_t)(64 * i) * NN];
    #pragma unroll
    for (int s = 0; s < 2; ++s) {
        fu[s]  = *(const half8*)&fP[(size_t)(64 + s * 16) * 32];
        lvu[s] = *(const floatx4*)&lP[64 + s * 16];
    }

    #pragma unroll 2
    for (int T = 0; T < NN / 64; ++T) {
        const int cur = T & 1, nxt = cur ^ 1;

        __syncthreads();              // A: prev PV's h_lds reads done; loads landed
        #pragma unroll
        for (int i = 0; i < 4; ++i)
            *(half8*)&h_lds[srow + 64 * i][sch * 8] = hpre[i];
        __syncthreads();              // B: h_lds(T) visible

        // ---- issue loads: h(T+1), f(T+2)/L(T+2) (drain at next barA)
        int ntn  = (T + 1) * 64; if (ntn  >= NN) ntn  = 0;
        int ntn2 = (T + 2) * 64; if (ntn2 >= NN) ntn2 -= NN;
        #pragma unroll
        for (int i = 0; i < 4; ++i)
            hpre[i] = *(const half8*)&hP[(size_t)(64 * i) * NN + ntn];
        #pragma unroll
        for (int s = 0; s < 2; ++s) {
            ff[s]  = *(const half8*)&fP[(size_t)(ntn2 + s * 16) * 32];
            lvf[s] = *(const floatx4*)&lP[ntn2 + s * 16];
        }

        // ---- S(T+1): wave's 32m x 32n strip -> PT[nxt] (VALU-heavy)
        #pragma unroll
        for (int u = 0; u < 2; ++u)
            #pragma unroll
            for (int s = 0; s < 2; ++s) {
                floatx4 S = __builtin_amdgcn_mfma_f32_16x16x32_f16(
                    fu[s], gS[u], (floatx4){0.f, 0.f, 0.f, 0.f}, 0, 0, 0);
                half4 p;
                p[0] = (half_t)exp2f(fmaf(S[0], 1.44269504f, lvu[s][0]));
                p[1] = (half_t)exp2f(fmaf(S[1], 1.44269504f, lvu[s][1]));
                p[2] = (half_t)exp2f(fmaf(S[2], 1.44269504f, lvu[s][2]));
                p[3] = (half_t)exp2f(fmaf(S[3], 1.44269504f, lvu[s][3]));
                *(half4*)&PT[nxt][smg + u * 16 + mc][snh + s * 16 + q * 4] = p;
            }

        // ---- PV(T): wave's 64c x 64m tile; 2A + 2B reads per k-chunk
        __builtin_amdgcn_s_setprio(1);
        #pragma unroll
        for (int ch = 0; ch < 4; ++ch) {
            half8 A0 = *(const half8*)&h_lds[cg + l31][ch * 16 + l5 * 8];
            half8 A1 = *(const half8*)&h_lds[cg + 32 + l31][ch * 16 + l5 * 8];
            half8 B0 = *(const half8*)&PT[cur][pmg + l31][ch * 16 + l5 * 8];
            half8 B1 = *(const half8*)&PT[cur][pmg + 32 + l31][ch * 16 + l5 * 8];
            acc[0][0] = __builtin_amdgcn_mfma_f32_32x32x16_f16(A0, B0, acc[0][0], 0, 0, 0);
            acc[0][1] = __builtin_amdgcn_mfma_f32_32x32x16_f16(A0, B1, acc[0][1], 0, 0, 0);
            acc[1][0] = __builtin_amdgcn_mfma_f32_32x32x16_f16(A1, B0, acc[1][0], 0, 0, 0);
            acc[1][1] = __builtin_amdgcn_mfma_f32_32x32x16_f16(A1, B1, acc[1][1], 0, 0, 0);
        }
        __builtin_amdgcn_s_setprio(0);

        // rotate f/L pipeline (hpre rotates in place)
        #pragma unroll
        for (int s = 0; s < 2; ++s) { fu[s] = ff[s]; lvu[s] = lvf[s]; }
    }

    // ---- epilogue: out = src + gamma * acc (D: col=l31->m, row pattern->c)
    const float gm = gamma[0];
    const float* srcb = src + (size_t)b * CC * NN;
    float* outb = out + (size_t)b * CC * NN;
    #pragma unroll
    for (int a = 0; a < 2; ++a)
        #pragma unroll
        for (int ms = 0; ms < 2; ++ms) {
            const int m = m0 + pmg + ms * 32 + l31;
            #pragma unroll
            for (int r = 0; r < 16; ++r) {
                int c = cg + a * 32 + (r & 3) + 8 * (r >> 2) + 4 * l5;
                size_t idx = (size_t)c * NN + m;
                outb[idx] = fmaf(gm, acc[a][ms][r], srcb[idx]);
            }
        }
}

// ---------------------------------------------------------------------------
extern "C" void kernel_launch(void* const* d_in, const int* in_sizes, int n_in,
                              void* d_out, int out_size, void* d_ws, size_t ws_size,
                              hipStream_t stream)
{
    const float* x   = (const float*)d_in[0];
    const float* y   = (const float*)d_in[1];
    const float* Wfx = (const float*)d_in[2];
    const float* bfx = (const float*)d_in[3];
    const float* Wgx = (const float*)d_in[4];
    const float* bgx = (const float*)d_in[5];
    const float* Whx = (const float*)d_in[6];
    const float* bhx = (const float*)d_in[7];
    const float* Wfy = (const float*)d_in[8];
    const float* bfy = (const float*)d_in[9];
    const float* Wgy = (const float*)d_in[10];
    const float* bgy = (const float*)d_in[11];
    const float* Why = (const float*)d_in[12];
    const float* bhy = (const float*)d_in[13];
    const float* gam = (const float*)d_in[14];

    const size_t SZ_XT = (size_t)BB * NN * CC;   // 4,194,304 halves
    const size_t SZ_FG = (size_t)BB * NN * 32;   // 524,288 halves
    half_t* xTx   = (half_t*)d_ws;               // (unused, layout kept)
    half_t* xTy   = xTx + SZ_XT;
    half_t* hx    = xTy + SZ_XT;                 // plain h[c][n]
    half_t* hy    = hx + SZ_XT;                  // plain h[c][n]
    half_t* fxT   = hy + SZ_XT;
    half_t* gxT   = fxT + SZ_FG;
    half_t* fyT   = gxT + SZ_FG;
    half_t* gyT   = fyT + SZ_FG;
    half_t* Wfx_h = gyT + SZ_FG;
    half_t* Wgx_h = Wfx_h + 32 * CC;
    half_t* Wfy_h = Wgx_h + 32 * CC;
    half_t* Wgy_h = Wfy_h + 32 * CC;
    half_t* Whx_h = Wgy_h + 32 * CC;
    half_t* Why_h = Whx_h + CC * CC;
    float*  Lx    = (float*)(Why_h + CC * CC);
    float*  Ly    = Lx + (size_t)BB * NN;

    float* outx = (float*)d_out;
    float* outy = outx + (size_t)BB * CC * NN;

    cvt_w_kernel<<<dim3(64, 6), 256, 0, stream>>>(Wfx, Wgx, Whx, Wfy, Wgy, Why,
                                                  Wfx_h, Wgx_h, Whx_h, Wfy_h, Wgy_h, Why_h);

    prep_kernel<<<dim3(64, 4, 2), 512, 0, stream>>>(
        x, y, Wfx_h, Wgx_h, Whx_h, Wfy_h, Wgy_h, Why_h,
        bfx, bgx, bhx, bfy, bgy, bhy,
        fxT, gxT, hx, fyT, gyT, hy);

    // att_x rows: fy vs gx -> Lx ; att_y rows: fx vs gy -> Ly
    stats_kernel<<<dim3(128, 4, 2), 256, 0, stream>>>(fyT, gxT, fxT, gyT, Lx, Ly);

    pv_kernel<<<dim3(32, 8), 512, 0, stream>>>(
        fyT, gxT, hx, Lx, x, outx,
        fxT, gyT, hy, Ly, y, outy, gam);
}